// Round 1
// baseline (494.000 us; speedup 1.0000x reference)
//
#include <hip/hip_runtime.h>
#include <hip/hip_bf16.h>

#define M_TOT 8192
#define N_TOT 4096
#define K_TOT 4096
#define BM 128
#define BN 128
#define BK 64

typedef short s16x8 __attribute__((ext_vector_type(8)));
typedef float f32x4 __attribute__((ext_vector_type(4)));

// fp32 -> bf16 round-to-nearest-even (inputs are finite/normal here)
__device__ __forceinline__ short f2bf(float f) {
    unsigned int u = __float_as_uint(f);
    u = (u + 0x7fffu + ((u >> 16) & 1u)) >> 16;
    return (short)u;
}

__global__ __launch_bounds__(256, 2)
void qlin_kernel(const float* __restrict__ x,
                 const int* __restrict__ qw,
                 const float* __restrict__ scales,
                 const float* __restrict__ zeros,
                 const float* __restrict__ bias,
                 float* __restrict__ out) {
    __shared__ short As[BM * BK];  // [row][k], 16B-granule XOR swizzled
    __shared__ short Bs[BN * BK];  // [col][k], same swizzle (holds W^T tile)

    const int tid = threadIdx.x;
    const int n0 = blockIdx.x * BN;
    const int m0 = blockIdx.y * BM;

    // ---- per-thread staging geometry ----
    // A: thread covers k-group kg (8 k's), rows row0+32*i
    const int a_kg   = tid & 7;
    const int a_row0 = tid >> 3;           // 0..31
    // B: thread owns one output column, r-groups rg0+2*i
    const int b_oloc = tid & 127;          // column within tile
    const int b_rg0  = tid >> 7;           // 0..1

    // per-column dequant constants: w = q*c0 + c1
    const int ocol = n0 + b_oloc;
    const float c0 = scales[ocol];
    const float c1 = -rintf(zeros[ocol] / c0) * c0;

    // ---- compute geometry ----
    const int lane = tid & 63;
    const int wv   = tid >> 6;             // 0..3
    const int wr   = wv >> 1;              // wave row (0..1)
    const int wc   = wv & 1;               // wave col (0..1)
    const int lrow = lane & 15;
    const int lk   = lane >> 4;            // 0..3

    f32x4 acc[4][4] = {};

    for (int kt = 0; kt < K_TOT / BK; ++kt) {
        const int k0 = kt * BK;

        // ---- stage A tile: 128x64 fp32 -> bf16 ----
        {
            const float* srcb = x + (size_t)(m0)*K_TOT + k0 + a_kg * 8;
            #pragma unroll
            for (int i = 0; i < 4; ++i) {
                const int row = a_row0 + 32 * i;
                const float4 f0 = *(const float4*)(srcb + (size_t)row * K_TOT);
                const float4 f1 = *(const float4*)(srcb + (size_t)row * K_TOT + 4);
                s16x8 v;
                v[0] = f2bf(f0.x); v[1] = f2bf(f0.y); v[2] = f2bf(f0.z); v[3] = f2bf(f0.w);
                v[4] = f2bf(f1.x); v[5] = f2bf(f1.y); v[6] = f2bf(f1.z); v[7] = f2bf(f1.w);
                *(s16x8*)&As[row * 64 + ((a_kg ^ (row & 7)) << 3)] = v;
            }
        }

        // ---- stage B tile: dequant int4 -> bf16, W^T layout [col][k] ----
        {
            const int rbase = k0 >> 1;  // packed-row base
            #pragma unroll
            for (int i = 0; i < 4; ++i) {
                const int rg = b_rg0 + 2 * i;   // 0..7 : covers k = rg*8 .. rg*8+7
                const int* qp = qw + (size_t)(rbase + rg * 4) * N_TOT + ocol;
                s16x8 v;
                #pragma unroll
                for (int rr = 0; rr < 4; ++rr) {
                    const int q = qp[(size_t)rr * N_TOT];
                    const float wl = fmaf((float)(q & 15), c0, c1);
                    const float wh = fmaf((float)((q >> 4) & 15), c0, c1);
                    v[2 * rr]     = f2bf(wl);
                    v[2 * rr + 1] = f2bf(wh);
                }
                *(s16x8*)&Bs[b_oloc * 64 + ((rg ^ (b_oloc & 7)) << 3)] = v;
            }
        }

        __syncthreads();

        // ---- MFMA compute: 2 k-slices of 32 ----
        #pragma unroll
        for (int ks = 0; ks < 2; ++ks) {
            const int slot = ks * 4 + lk;
            s16x8 a[4], b[4];
            #pragma unroll
            for (int mi = 0; mi < 4; ++mi) {
                const int row = wr * 64 + mi * 16 + lrow;
                a[mi] = *(const s16x8*)&As[row * 64 + ((slot ^ (row & 7)) << 3)];
            }
            #pragma unroll
            for (int ni = 0; ni < 4; ++ni) {
                const int row = wc * 64 + ni * 16 + lrow;
                b[ni] = *(const s16x8*)&Bs[row * 64 + ((slot ^ (row & 7)) << 3)];
            }
            #pragma unroll
            for (int mi = 0; mi < 4; ++mi)
                #pragma unroll
                for (int ni = 0; ni < 4; ++ni)
                    acc[mi][ni] = __builtin_amdgcn_mfma_f32_16x16x32_bf16(
                        a[mi], b[ni], acc[mi][ni], 0, 0, 0);
        }

        __syncthreads();
    }

    // ---- epilogue: C/D layout col = lane&15, row = (lane>>4)*4 + j ----
    #pragma unroll
    for (int mi = 0; mi < 4; ++mi) {
        const int rg = m0 + wr * 64 + mi * 16 + lk * 4;
        #pragma unroll
        for (int ni = 0; ni < 4; ++ni) {
            const int cg = n0 + wc * 64 + ni * 16 + lrow;
            const float bs = bias[cg];
            #pragma unroll
            for (int j = 0; j < 4; ++j)
                out[(size_t)(rg + j) * N_TOT + cg] = acc[mi][ni][j] + bs;
        }
    }
}

extern "C" void kernel_launch(void* const* d_in, const int* in_sizes, int n_in,
                              void* d_out, int out_size, void* d_ws, size_t ws_size,
                              hipStream_t stream) {
    const float* x      = (const float*)d_in[0];
    const int*   qw     = (const int*)d_in[1];
    const float* scales = (const float*)d_in[2];
    const float* zeros  = (const float*)d_in[3];
    const float* bias   = (const float*)d_in[4];
    float* out = (float*)d_out;

    dim3 grid(N_TOT / BN, M_TOT / BM);
    hipLaunchKernelGGL(qlin_kernel, grid, dim3(256), 0, stream,
                       x, qw, scales, zeros, bias, out);
}

// Round 2
// 324.584 us; speedup vs baseline: 1.5219x; 1.5219x over previous
//
#include <hip/hip_runtime.h>
#include <hip/hip_bf16.h>
#include <stdint.h>

#define M_TOT 8192
#define N_TOT 4096
#define K_TOT 4096
#define BM 128
#define BN 128
#define BK 64

typedef short s16x8 __attribute__((ext_vector_type(8)));
typedef float f32x4 __attribute__((ext_vector_type(4)));

// fp32 -> bf16 round-to-nearest-even
__device__ __forceinline__ short f2bf(float f) {
    unsigned int u = __float_as_uint(f);
    u = (u + 0x7fffu + ((u >> 16) & 1u)) >> 16;
    return (short)u;
}

__device__ __forceinline__ void async_copy16(const void* g, void* l) {
    __builtin_amdgcn_global_load_lds(
        (const __attribute__((address_space(1))) void*)g,
        (__attribute__((address_space(3))) void*)l, 16, 0, 0);
}

// ---------------- pass 1a: x fp32 -> bf16 ----------------
__global__ __launch_bounds__(256)
void cvt_x(const float* __restrict__ x, short* __restrict__ xbf, int n8) {
    const int idx = blockIdx.x * blockDim.x + threadIdx.x;
    const int stride = gridDim.x * blockDim.x;
    for (int i = idx; i < n8; i += stride) {
        const float4 f0 = ((const float4*)x)[(size_t)i * 2];
        const float4 f1 = ((const float4*)x)[(size_t)i * 2 + 1];
        s16x8 v;
        v[0] = f2bf(f0.x); v[1] = f2bf(f0.y); v[2] = f2bf(f0.z); v[3] = f2bf(f0.w);
        v[4] = f2bf(f1.x); v[5] = f2bf(f1.y); v[6] = f2bf(f1.z); v[7] = f2bf(f1.w);
        ((s16x8*)xbf)[i] = v;
    }
}

// ---------------- pass 1b: int4 -> bf16 W^T [OUT][IN] ----------------
__global__ __launch_bounds__(256)
void dequant_w(const int* __restrict__ qw, const float* __restrict__ scales,
               const float* __restrict__ zeros, short* __restrict__ wt) {
    const int o = blockIdx.x * 256 + threadIdx.x;
    const int r0 = blockIdx.y * 32;                    // packed-row base
    const float c0 = scales[o];
    const float c1 = -rintf(zeros[o] / c0) * c0;
    #pragma unroll
    for (int j = 0; j < 8; ++j) {
        s16x8 v;
        #pragma unroll
        for (int i = 0; i < 4; ++i) {
            const int q = qw[(size_t)(r0 + j * 4 + i) * N_TOT + o];   // coalesced across lanes
            v[2 * i]     = f2bf(fmaf((float)(q & 15), c0, c1));
            v[2 * i + 1] = f2bf(fmaf((float)((q >> 4) & 15), c0, c1));
        }
        *(s16x8*)&wt[(size_t)o * K_TOT + r0 * 2 + j * 8] = v;
    }
}

// ---------------- pass 2: bf16 GEMM (m97 structure) ----------------
__global__ __launch_bounds__(256, 2)
void gemm_bf16(const short* __restrict__ xbf, const short* __restrict__ wt,
               const float* __restrict__ bias, float* __restrict__ out) {
    __shared__ short As[BM * BK];   // linear granules; data pre-swizzled at source
    __shared__ short Bs[BN * BK];

    const int tid = threadIdx.x;
    const int n0 = blockIdx.x * BN;
    const int m0 = blockIdx.y * BM;
    const int lane = tid & 63;
    const int wv = tid >> 6;
    const int wr = wv >> 1, wc = wv & 1;
    const int lrow = lane & 15, lk = lane >> 4;

    f32x4 acc[4][4] = {};

    for (int kt = 0; kt < K_TOT / BK; ++kt) {
        const int k0 = kt * BK;
        // stage A: 1024 granules of 16B; LDS granule (row,c) <- global granule (row, c^(row&7))
        #pragma unroll
        for (int i = 0; i < 4; ++i) {
            const int g = i * 256 + wv * 64 + lane;
            const int row = g >> 3, c = g & 7;
            async_copy16(xbf + (size_t)(m0 + row) * K_TOT + k0 + ((c ^ (row & 7)) << 3),
                         &As[(i * 256 + wv * 64) * 8]);
        }
        // stage B (W^T rows = output columns)
        #pragma unroll
        for (int i = 0; i < 4; ++i) {
            const int g = i * 256 + wv * 64 + lane;
            const int row = g >> 3, c = g & 7;
            async_copy16(wt + (size_t)(n0 + row) * K_TOT + k0 + ((c ^ (row & 7)) << 3),
                         &Bs[(i * 256 + wv * 64) * 8]);
        }
        __syncthreads();   // vmcnt(0) drain + barrier

        #pragma unroll
        for (int ks = 0; ks < 2; ++ks) {
            const int slot = ks * 4 + lk;
            s16x8 a[4], b[4];
            #pragma unroll
            for (int mi = 0; mi < 4; ++mi) {
                const int row = wr * 64 + mi * 16 + lrow;
                a[mi] = *(const s16x8*)&As[row * 64 + ((slot ^ (row & 7)) << 3)];
            }
            #pragma unroll
            for (int ni = 0; ni < 4; ++ni) {
                const int row = wc * 64 + ni * 16 + lrow;
                b[ni] = *(const s16x8*)&Bs[row * 64 + ((slot ^ (row & 7)) << 3)];
            }
            #pragma unroll
            for (int mi = 0; mi < 4; ++mi)
                #pragma unroll
                for (int ni = 0; ni < 4; ++ni)
                    acc[mi][ni] = __builtin_amdgcn_mfma_f32_16x16x32_bf16(
                        a[mi], b[ni], acc[mi][ni], 0, 0, 0);
        }
        __syncthreads();
    }

    #pragma unroll
    for (int mi = 0; mi < 4; ++mi) {
        const int rg = m0 + wr * 64 + mi * 16 + lk * 4;
        #pragma unroll
        for (int ni = 0; ni < 4; ++ni) {
            const int cg = n0 + wc * 64 + ni * 16 + lrow;
            const float bs = bias[cg];
            #pragma unroll
            for (int j = 0; j < 4; ++j)
                out[(size_t)(rg + j) * N_TOT + cg] = acc[mi][ni][j] + bs;
        }
    }
}

// ---------------- fallback: round-1 fused kernel ----------------
__global__ __launch_bounds__(256, 2)
void qlin_fused(const float* __restrict__ x,
                const int* __restrict__ qw,
                const float* __restrict__ scales,
                const float* __restrict__ zeros,
                const float* __restrict__ bias,
                float* __restrict__ out) {
    __shared__ short As[BM * BK];
    __shared__ short Bs[BN * BK];

    const int tid = threadIdx.x;
    const int n0 = blockIdx.x * BN;
    const int m0 = blockIdx.y * BM;

    const int a_kg   = tid & 7;
    const int a_row0 = tid >> 3;
    const int b_oloc = tid & 127;
    const int b_rg0  = tid >> 7;

    const int ocol = n0 + b_oloc;
    const float c0 = scales[ocol];
    const float c1 = -rintf(zeros[ocol] / c0) * c0;

    const int lane = tid & 63;
    const int wv   = tid >> 6;
    const int wr   = wv >> 1;
    const int wc   = wv & 1;
    const int lrow = lane & 15;
    const int lk   = lane >> 4;

    f32x4 acc[4][4] = {};

    for (int kt = 0; kt < K_TOT / BK; ++kt) {
        const int k0 = kt * BK;
        {
            const float* srcb = x + (size_t)(m0)*K_TOT + k0 + a_kg * 8;
            #pragma unroll
            for (int i = 0; i < 4; ++i) {
                const int row = a_row0 + 32 * i;
                const float4 f0 = *(const float4*)(srcb + (size_t)row * K_TOT);
                const float4 f1 = *(const float4*)(srcb + (size_t)row * K_TOT + 4);
                s16x8 v;
                v[0] = f2bf(f0.x); v[1] = f2bf(f0.y); v[2] = f2bf(f0.z); v[3] = f2bf(f0.w);
                v[4] = f2bf(f1.x); v[5] = f2bf(f1.y); v[6] = f2bf(f1.z); v[7] = f2bf(f1.w);
                *(s16x8*)&As[row * 64 + ((a_kg ^ (row & 7)) << 3)] = v;
            }
        }
        {
            const int rbase = k0 >> 1;
            #pragma unroll
            for (int i = 0; i < 4; ++i) {
                const int rg = b_rg0 + 2 * i;
                const int* qp = qw + (size_t)(rbase + rg * 4) * N_TOT + ocol;
                s16x8 v;
                #pragma unroll
                for (int rr = 0; rr < 4; ++rr) {
                    const int q = qp[(size_t)rr * N_TOT];
                    v[2 * rr]     = f2bf(fmaf((float)(q & 15), c0, c1));
                    v[2 * rr + 1] = f2bf(fmaf((float)((q >> 4) & 15), c0, c1));
                }
                *(s16x8*)&Bs[b_oloc * 64 + ((rg ^ (b_oloc & 7)) << 3)] = v;
            }
        }
        __syncthreads();
        #pragma unroll
        for (int ks = 0; ks < 2; ++ks) {
            const int slot = ks * 4 + lk;
            s16x8 a[4], b[4];
            #pragma unroll
            for (int mi = 0; mi < 4; ++mi) {
                const int row = wr * 64 + mi * 16 + lrow;
                a[mi] = *(const s16x8*)&As[row * 64 + ((slot ^ (row & 7)) << 3)];
            }
            #pragma unroll
            for (int ni = 0; ni < 4; ++ni) {
                const int row = wc * 64 + ni * 16 + lrow;
                b[ni] = *(const s16x8*)&Bs[row * 64 + ((slot ^ (row & 7)) << 3)];
            }
            #pragma unroll
            for (int mi = 0; mi < 4; ++mi)
                #pragma unroll
                for (int ni = 0; ni < 4; ++ni)
                    acc[mi][ni] = __builtin_amdgcn_mfma_f32_16x16x32_bf16(
                        a[mi], b[ni], acc[mi][ni], 0, 0, 0);
        }
        __syncthreads();
    }

    #pragma unroll
    for (int mi = 0; mi < 4; ++mi) {
        const int rg = m0 + wr * 64 + mi * 16 + lk * 4;
        #pragma unroll
        for (int ni = 0; ni < 4; ++ni) {
            const int cg = n0 + wc * 64 + ni * 16 + lrow;
            const float bs = bias[cg];
            #pragma unroll
            for (int j = 0; j < 4; ++j)
                out[(size_t)(rg + j) * N_TOT + cg] = acc[mi][ni][j] + bs;
        }
    }
}

extern "C" void kernel_launch(void* const* d_in, const int* in_sizes, int n_in,
                              void* d_out, int out_size, void* d_ws, size_t ws_size,
                              hipStream_t stream) {
    const float* x      = (const float*)d_in[0];
    const int*   qw     = (const int*)d_in[1];
    const float* scales = (const float*)d_in[2];
    const float* zeros  = (const float*)d_in[3];
    const float* bias   = (const float*)d_in[4];
    float* out = (float*)d_out;

    const size_t XBF_BYTES = (size_t)M_TOT * K_TOT * 2;   // 64 MiB
    const size_t WT_BYTES  = (size_t)N_TOT * K_TOT * 2;   // 32 MiB

    if (ws_size >= XBF_BYTES + WT_BYTES) {
        short* xbf = (short*)d_ws;
        short* wt  = (short*)((char*)d_ws + XBF_BYTES);

        hipLaunchKernelGGL(cvt_x, dim3(2048), dim3(256), 0, stream,
                           x, xbf, (int)((size_t)M_TOT * K_TOT / 8));
        hipLaunchKernelGGL(dequant_w, dim3(N_TOT / 256, K_TOT / 64), dim3(256), 0, stream,
                           qw, scales, zeros, wt);
        hipLaunchKernelGGL(gemm_bf16, dim3(N_TOT / BN, M_TOT / BM), dim3(256), 0, stream,
                           xbf, wt, bias, out);
    } else {
        hipLaunchKernelGGL(qlin_fused, dim3(N_TOT / BN, M_TOT / BM), dim3(256), 0, stream,
                           x, qw, scales, zeros, bias, out);
    }
}